// Round 1
// baseline (433.780 us; speedup 1.0000x reference)
//
#include <hip/hip_runtime.h>
#include <math.h>

#define D 128
#define KTGT 16

// ---------------------------------------------------------------------------
// K1: Wqk[d][c] = sum_j Wq[j][d] * Wk[j][c]   (i.e. Wq^T @ Wk)
//     WvT[d][c] = Wv[c][d]
// Exact reformulation: scores = tgt . (src @ Wqk),  out = ctx @ Wv^T.
// ---------------------------------------------------------------------------
__global__ void prep_kernel(const float* __restrict__ Wq,
                            const float* __restrict__ Wk,
                            const float* __restrict__ Wv,
                            float* __restrict__ Wqk,
                            float* __restrict__ WvT) {
    const int drow = blockIdx.x;   // 0..127
    const int c    = threadIdx.x;  // 0..127
    float acc = 0.0f;
    #pragma unroll 8
    for (int j = 0; j < D; ++j)
        acc = fmaf(Wq[j * D + drow], Wk[j * D + c], acc);
    Wqk[drow * D + c] = acc;
    WvT[drow * D + c] = Wv[c * D + drow];
}

// ---------------------------------------------------------------------------
// K2/K4: C[r][c] = sum_d A[r][d] * B[d][c] for 32 rows per block.
// 256 threads: thread = (rblk = tid>>5 -> 4 rows, cblk = tid&31 -> 4 cols),
// A tile staged in LDS (reads are broadcast), B read from L2 as float4.
// Safe to run in-place (C == A): stage-then-sync, block only touches own rows.
// ---------------------------------------------------------------------------
__global__ __launch_bounds__(256) void rowgemm_kernel(const float* __restrict__ A,
                                                      const float* __restrict__ B,
                                                      float* __restrict__ C) {
    __shared__ float Alds[32][D];
    const int r0 = blockIdx.x * 32;
    {
        const float4* Ag = reinterpret_cast<const float4*>(A + (size_t)r0 * D);
        float4* Al = reinterpret_cast<float4*>(&Alds[0][0]);
        #pragma unroll
        for (int i = 0; i < 4; ++i)
            Al[threadIdx.x + i * 256] = Ag[threadIdx.x + i * 256];
    }
    __syncthreads();

    const int cblk = threadIdx.x & 31;  // cols cblk*4 .. +3
    const int rblk = threadIdx.x >> 5;  // rows rblk*4 .. +3
    float acc[4][4] = {};
    const float4* B4 = reinterpret_cast<const float4*>(B);

    for (int d0 = 0; d0 < D; d0 += 4) {
        float4 a[4];
        #pragma unroll
        for (int j = 0; j < 4; ++j)
            a[j] = *reinterpret_cast<const float4*>(&Alds[rblk * 4 + j][d0]);
        #pragma unroll
        for (int dd = 0; dd < 4; ++dd) {
            float4 w = B4[(d0 + dd) * 32 + cblk];
            #pragma unroll
            for (int j = 0; j < 4; ++j) {
                float aj = (&a[j].x)[dd];
                acc[j][0] = fmaf(aj, w.x, acc[j][0]);
                acc[j][1] = fmaf(aj, w.y, acc[j][1]);
                acc[j][2] = fmaf(aj, w.z, acc[j][2]);
                acc[j][3] = fmaf(aj, w.w, acc[j][3]);
            }
        }
    }

    #pragma unroll
    for (int j = 0; j < 4; ++j) {
        float4 o = make_float4(acc[j][0], acc[j][1], acc[j][2], acc[j][3]);
        *reinterpret_cast<float4*>(C + (size_t)(r0 + rblk * 4 + j) * D + cblk * 4) = o;
    }
}

// ---------------------------------------------------------------------------
// K3: per (b,n) row r (one wave each, grid-stride):
//   scores[k] = (tgt[r,k,:] . S[r,:]) * 1/sqrt(128), softmax over k=16,
//   ctx[r,:]  = sum_k attn[k] * tgt[r,k,:]        (written in-place over S)
// Lane l owns float4 d-chunk d4=l&31; half h=l>>5 owns k = 2i+h, i=0..7.
// ---------------------------------------------------------------------------
__global__ __launch_bounds__(256) void attn_kernel(const float* __restrict__ tgt,
                                                   float* __restrict__ SC,
                                                   int nrows) {
    const int lane = threadIdx.x & 63;
    const int wid  = (int)((blockIdx.x * blockDim.x + threadIdx.x) >> 6);
    const int nw   = (int)((gridDim.x * blockDim.x) >> 6);
    const int d4   = lane & 31;
    const float scale = 0.088388347648318447f;  // 1/sqrt(128)

    for (int r = wid; r < nrows; r += nw) {
        float4 Sv = *reinterpret_cast<const float4*>(SC + (size_t)r * D + d4 * 4);
        const float4* T4 = reinterpret_cast<const float4*>(tgt + (size_t)r * KTGT * D);

        float4 tv[8];
        float p[8];
        #pragma unroll
        for (int i = 0; i < 8; ++i) {
            tv[i] = T4[i * 64 + lane];  // k = 2i + (lane>>5), chunk d4
            p[i] = tv[i].x * Sv.x + tv[i].y * Sv.y + tv[i].z * Sv.z + tv[i].w * Sv.w;
        }
        // reduce over the 32 d-chunks (within each 32-lane half)
        #pragma unroll
        for (int m = 1; m <= 16; m <<= 1) {
            #pragma unroll
            for (int i = 0; i < 8; ++i)
                p[i] += __shfl_xor(p[i], m, 64);
        }
        float q[8];
        #pragma unroll
        for (int i = 0; i < 8; ++i) {
            p[i] *= scale;                   // score for k = 2i + half
            q[i] = __shfl_xor(p[i], 32, 64); // score for k = 2i + (1-half)
        }
        float mx = -1e30f;
        #pragma unroll
        for (int i = 0; i < 8; ++i) mx = fmaxf(mx, fmaxf(p[i], q[i]));
        float sum = 0.0f;
        float ep[8];
        #pragma unroll
        for (int i = 0; i < 8; ++i) {
            ep[i] = __expf(p[i] - mx);
            float eq = __expf(q[i] - mx);
            sum += ep[i] + eq;
        }
        const float inv = 1.0f / sum;
        float cx = 0.f, cy = 0.f, cz = 0.f, cw = 0.f;
        #pragma unroll
        for (int i = 0; i < 8; ++i) {
            float w = ep[i] * inv;
            cx = fmaf(w, tv[i].x, cx);
            cy = fmaf(w, tv[i].y, cy);
            cz = fmaf(w, tv[i].z, cz);
            cw = fmaf(w, tv[i].w, cw);
        }
        // add the partner half's 8 k's (same d-chunk, complementary k set)
        cx += __shfl_xor(cx, 32, 64);
        cy += __shfl_xor(cy, 32, 64);
        cz += __shfl_xor(cz, 32, 64);
        cw += __shfl_xor(cw, 32, 64);
        if (lane < 32) {
            float4 o = make_float4(cx, cy, cz, cw);
            *reinterpret_cast<float4*>(SC + (size_t)r * D + d4 * 4) = o;
        }
    }
}

extern "C" void kernel_launch(void* const* d_in, const int* in_sizes, int n_in,
                              void* d_out, int out_size, void* d_ws, size_t ws_size,
                              hipStream_t stream) {
    const float* src = (const float*)d_in[0];
    const float* tgt = (const float*)d_in[1];
    const float* Wq  = (const float*)d_in[2];
    const float* Wk  = (const float*)d_in[3];
    const float* Wv  = (const float*)d_in[4];
    float* out = (float*)d_out;

    float* Wqk = (float*)d_ws;          // 128*128 f32 = 64 KB
    float* WvT = Wqk + D * D;           // 128*128 f32 = 64 KB

    const int nrows = in_sizes[0] / D;  // b*n = 32768

    // 1) tiny weight precompute
    prep_kernel<<<D, D, 0, stream>>>(Wq, Wk, Wv, Wqk, WvT);
    // 2) S = src @ Wqk  -> d_out
    rowgemm_kernel<<<nrows / 32, 256, 0, stream>>>(src, Wqk, out);
    // 3) scores/softmax/ctx, in-place over d_out
    attn_kernel<<<2048, 256, 0, stream>>>(tgt, out, nrows);
    // 4) out = ctx @ Wv^T, in-place per 32-row block
    rowgemm_kernel<<<nrows / 32, 256, 0, stream>>>(out, WvT, out);
}